// Round 4
// baseline (170.246 us; speedup 1.0000x reference)
//
#include <hip/hip_runtime.h>
#include <stdint.h>

#define IN_F  4096
#define OUT_F 4096
#define BW    512
#define TN    256    // col-tile width (B window granularity)
#define WB2   1280   // padded k-window per 256-col tile: [bcol-512, bcol+768)
#define BM    128
#define BN    256
#define BUFSZ 49152  // per ring slot: A 16 KB + B 32 KB

typedef __bf16 bf16x8 __attribute__((ext_vector_type(8)));
typedef float  f32x4  __attribute__((ext_vector_type(4)));

__device__ __forceinline__ int band_start(int o) {
    if (o <= 512)  return o * 513 + ((o * (o - 1)) >> 1);
    if (o <= 3584) return 393472 + (o - 512) * 1025;
    const int d = o - 3584;
    return 3542272 + (((1024 + 4609 - o) * d) >> 1);
}

__device__ __forceinline__ uint16_t f32_to_bf16(float f) {
    uint32_t u = __builtin_bit_cast(uint32_t, f);
    u += 0x7FFFu + ((u >> 16) & 1u);   // RNE
    return (uint16_t)(u >> 16);
}

// ---- pass 1: x fp32 -> bf16 dense [M][4096]
__global__ __launch_bounds__(256) void cvt_x(const float* __restrict__ x,
                                             uint16_t* __restrict__ xb, int n4) {
    const int stride = gridDim.x * 256;
    for (int i = blockIdx.x * 256 + threadIdx.x; i < n4; i += stride) {
        const float4 v = reinterpret_cast<const float4*>(x)[i];
        const uint32_t lo = (uint32_t)f32_to_bf16(v.x) | ((uint32_t)f32_to_bf16(v.y) << 16);
        const uint32_t hi = (uint32_t)f32_to_bf16(v.z) | ((uint32_t)f32_to_bf16(v.w) << 16);
        reinterpret_cast<uint2*>(xb)[i] = make_uint2(lo, hi);
    }
}

// ---- pass 2: densify band -> wd[o][j], j indexes k = (o&~255)-512+j, zero outside band
__global__ __launch_bounds__(256) void cvt_w(const float* __restrict__ wv,
                                             uint16_t* __restrict__ wd) {
    const int o = blockIdx.y;
    const int j = blockIdx.x * 256 + threadIdx.x;     // 0..1279
    const int i = (o & ~(TN - 1)) - BW + j;
    uint16_t v = 0;
    if (i >= o - BW && i <= o + BW && i >= 0 && i < IN_F) {
        const int lo = (o > BW) ? (o - BW) : 0;
        v = f32_to_bf16(wv[band_start(o) + (i - lo)]);
    }
    wd[o * WB2 + j] = v;
}

// ---- pass 3: 128x256 tile, BK=64, ring-3, ONE barrier + ONE counted vmcnt per tile
__global__ __launch_bounds__(512, 2) void band_gemm_v3(
    const uint16_t* __restrict__ xb,
    const uint16_t* __restrict__ wd,
    const float* __restrict__ bias,
    float* __restrict__ out)
{
    __shared__ __align__(128) uint8_t lds[3 * BUFSZ];   // 144 KB

    // XCD-aware bijective swizzle (nwg = 1024, %8 == 0); by-grouped per XCD
    const int id  = blockIdx.x;
    const int cpx = gridDim.x >> 3;
    const int wg  = (id & 7) * cpx + (id >> 3);
    const int bx  = wg & 15;                 // col tile (256 wide)
    const int by  = wg >> 4;                 // row tile (128 tall)
    const int brow = by * BM;
    const int bcol = bx * TN;

    const int wlo    = bcol - BW;
    const int kstart = wlo > 0 ? wlo : 0;                       // multiple of 256
    const int kend   = (bcol + TN + BW) < IN_F ? (bcol + TN + BW) : IN_F;
    const int nt     = (kend - kstart) >> 6;                    // 12..20 K64 tiles
    const int j0     = kstart - wlo;                            // 0/256/512

    const int tid  = threadIdx.x;
    const int w    = tid >> 6;
    const int lane = tid & 63;
    const int ln   = lane & 15;
    const int kc   = lane >> 4;
    const int wm   = w >> 2;                 // 0..1  (M half, 64 rows)
    const int wn   = w & 3;                  // 0..3  (N quarter, 64 cols)

    // ---- staging geometry: rounds of 8 KB (64 rows x 128 B), 512 thr x 16 B
    // LDS(row, c) holds global chunk c ^ (row & 7)  [chunk = 16 B]
    const int srow = tid >> 3;               // 0..63 within round
    const int csrc = (tid & 7) ^ (srow & 7);
    const uint16_t* aSrc = xb + (size_t)(brow + srow) * IN_F + kstart + csrc * 8;
    const uint16_t* bSrc = wd + (size_t)(bcol + srow) * WB2 + j0 + csrc * 8;

#define GLOAD(srcp, dst_off)                                                             \
    __builtin_amdgcn_global_load_lds(                                                    \
        (const __attribute__((address_space(1))) uint32_t*)(srcp),                       \
        (__attribute__((address_space(3))) uint32_t*)(lds + (dst_off) + (w << 10)),      \
        16, 0, 0)

    // stage tile ts into ring slot sb (6 gloads/wave): A 2 rounds, B 4 rounds
#define STAGE(ts_, sb_) {                                                                \
        const uint16_t* as_ = aSrc + (ts_) * 64;                                         \
        const uint16_t* bs_ = bSrc + (ts_) * 64;                                         \
        GLOAD(as_,                       (sb_) + 0);                                     \
        GLOAD(as_ + (size_t)64 * IN_F,   (sb_) + 8192);                                  \
        GLOAD(bs_,                       (sb_) + 16384);                                 \
        GLOAD(bs_ + (size_t)64  * WB2,   (sb_) + 24576);                                 \
        GLOAD(bs_ + (size_t)128 * WB2,   (sb_) + 32768);                                 \
        GLOAD(bs_ + (size_t)192 * WB2,   (sb_) + 40960); }

    // ---- fragment LDS offsets (k-step 0); k-step 1 = offset ^ 64
    const int cswz = (kc ^ (ln & 7)) << 4;
    int aOff[4], bOff[4];
    #pragma unroll
    for (int a = 0; a < 4; ++a) aOff[a] = ((wm * 64 + a * 16 + ln) << 7) + cswz;
    #pragma unroll
    for (int b = 0; b < 4; ++b) bOff[b] = 16384 + ((wn * 64 + b * 16 + ln) << 7) + cswz;

    f32x4 acc[4][4] = {};

    // prologue: stage tiles 0,1 -> slots 0,1 ; wait tile 0 (keep 6 in flight)
    STAGE(0, 0);
    STAGE(1, BUFSZ);
    asm volatile("s_waitcnt vmcnt(6)" ::: "memory");
    __builtin_amdgcn_s_barrier();

    int cur = 0, sb = 2 * BUFSZ;
    for (int t = 0; t < nt; ++t) {
        bf16x8 af0[4], bf0[4], af1[4], bf1[4];
        #pragma unroll
        for (int a = 0; a < 4; ++a) af0[a] = *(const bf16x8*)(lds + cur + aOff[a]);
        #pragma unroll
        for (int b = 0; b < 4; ++b) bf0[b] = *(const bf16x8*)(lds + cur + bOff[b]);

        const bool pf = (t + 2) < nt;
        if (pf) STAGE(t + 2, sb);

        #pragma unroll
        for (int a = 0; a < 4; ++a) af1[a] = *(const bf16x8*)(lds + cur + (aOff[a] ^ 64));
        #pragma unroll
        for (int b = 0; b < 4; ++b) bf1[b] = *(const bf16x8*)(lds + cur + (bOff[b] ^ 64));

        __builtin_amdgcn_s_setprio(1);
        #pragma unroll
        for (int a = 0; a < 4; ++a)
            #pragma unroll
            for (int b = 0; b < 4; ++b)
                acc[a][b] = __builtin_amdgcn_mfma_f32_16x16x32_bf16(af0[a], bf0[b], acc[a][b], 0, 0, 0);
        #pragma unroll
        for (int a = 0; a < 4; ++a)
            #pragma unroll
            for (int b = 0; b < 4; ++b)
                acc[a][b] = __builtin_amdgcn_mfma_f32_16x16x32_bf16(af1[a], bf1[b], acc[a][b], 0, 0, 0);
        __builtin_amdgcn_s_setprio(0);

        // boundary: tile t+1 must be resident (its 6 loads are the oldest in flight)
        if (pf) { asm volatile("s_waitcnt vmcnt(6)" ::: "memory"); }
        else    { asm volatile("s_waitcnt vmcnt(0)" ::: "memory"); }
        asm volatile("" ::: "memory");
        __builtin_amdgcn_s_barrier();
        asm volatile("" ::: "memory");

        cur += BUFSZ; if (cur == 3 * BUFSZ) cur = 0;
        sb  += BUFSZ; if (sb  == 3 * BUFSZ) sb  = 0;
    }
#undef STAGE
#undef GLOAD

    // ---- epilogue: C/D map col = lane&15, row = (lane>>4)*4 + q
    const int ocol = bcol + wn * 64 + ln;
    float bsv[4];
    #pragma unroll
    for (int b = 0; b < 4; ++b) bsv[b] = bias[ocol + b * 16];

    #pragma unroll
    for (int a = 0; a < 4; ++a) {
        #pragma unroll
        for (int q = 0; q < 4; ++q) {
            const int row = brow + wm * 64 + a * 16 + (kc << 2) + q;
            float* po = out + (size_t)row * OUT_F + ocol;
            #pragma unroll
            for (int b = 0; b < 4; ++b)
                po[b * 16] = acc[a][b][q] + bsv[b];
        }
    }
}

// ---- fallback (ws too small / odd M): fp32 tiled kernel, known correct
__global__ __launch_bounds__(256) void band_gemm_f32(
    const float* __restrict__ x, const float* __restrict__ wv,
    const float* __restrict__ bias, float* __restrict__ out, int M)
{
    __shared__ float Xs[128][33];
    __shared__ float Ws[32][130];
    const int tid = threadIdx.x;
    const int tx = tid & 15, ty = tid >> 4;
    const int bcol = blockIdx.x * 128, brow = blockIdx.y * 128;
    const int klo = (bcol >= BW) ? (bcol - BW) : 0;
    const int khi = min(IN_F, bcol + 128 + BW);
    float acc[8][8];
    #pragma unroll
    for (int a = 0; a < 8; ++a)
        #pragma unroll
        for (int b = 0; b < 8; ++b) acc[a][b] = 0.f;
    const int xc4 = (tid & 7) * 4, xr0 = tid >> 3;
    const int wc = tid & 31, wr0 = tid >> 5;
    for (int k0 = klo; k0 < khi; k0 += 32) {
        #pragma unroll
        for (int p = 0; p < 4; ++p) {
            const int r = xr0 + 32 * p;
            const float4 v = *reinterpret_cast<const float4*>(&x[(size_t)(brow + r) * IN_F + (k0 + xc4)]);
            Xs[r][xc4 + 0] = v.x; Xs[r][xc4 + 1] = v.y; Xs[r][xc4 + 2] = v.z; Xs[r][xc4 + 3] = v.w;
        }
        const int i = k0 + wc;
        #pragma unroll
        for (int p = 0; p < 16; ++p) {
            const int r = wr0 + 8 * p;
            const int o = bcol + r;
            const int lo = (o >= BW) ? (o - BW) : 0;
            float v = 0.f;
            if (i >= o - BW && i <= o + BW) v = wv[band_start(o) + (i - lo)];
            Ws[wc][r] = v;
        }
        __syncthreads();
        #pragma unroll
        for (int k = 0; k < 32; ++k) {
            float am[8];
            #pragma unroll
            for (int a = 0; a < 8; ++a) am[a] = Xs[ty * 8 + a][k];
            float bo[8];
            #pragma unroll
            for (int b = 0; b < 4; ++b) { bo[b] = Ws[k][tx * 4 + b]; bo[4 + b] = Ws[k][tx * 4 + 64 + b]; }
            #pragma unroll
            for (int a = 0; a < 8; ++a)
                #pragma unroll
                for (int b = 0; b < 8; ++b) acc[a][b] = fmaf(am[a], bo[b], acc[a][b]);
        }
        __syncthreads();
    }
    #pragma unroll
    for (int a = 0; a < 8; ++a) {
        const size_t row = (size_t)(brow + ty * 8 + a);
        #pragma unroll
        for (int b = 0; b < 4; ++b) {
            out[row * OUT_F + bcol + tx * 4 + b]      = acc[a][b]     + bias[bcol + tx * 4 + b];
            out[row * OUT_F + bcol + tx * 4 + 64 + b] = acc[a][4 + b] + bias[bcol + tx * 4 + 64 + b];
        }
    }
}

extern "C" void kernel_launch(void* const* d_in, const int* in_sizes, int n_in,
                              void* d_out, int out_size, void* d_ws, size_t ws_size,
                              hipStream_t stream) {
    const float* x    = (const float*)d_in[0];
    const float* wv   = (const float*)d_in[1];
    const float* bias = (const float*)d_in[2];
    float* out        = (float*)d_out;

    const int M = in_sizes[0] / IN_F;                         // 8192
    const size_t xb_bytes = (size_t)M * IN_F * 2;             // 64 MB
    const size_t wd_bytes = (size_t)OUT_F * WB2 * 2;          // 10.5 MB

    if (ws_size >= xb_bytes + wd_bytes && (M % BM) == 0) {
        uint16_t* xb  = (uint16_t*)d_ws;
        uint16_t* wdp = (uint16_t*)((uint8_t*)d_ws + xb_bytes);
        cvt_x<<<2048, 256, 0, stream>>>(x, xb, M * IN_F / 4);
        cvt_w<<<dim3(WB2 / 256, OUT_F), 256, 0, stream>>>(wv, wdp);
        band_gemm_v3<<<(M / BM) * (OUT_F / BN), 512, 0, stream>>>(xb, wdp, bias, out);
    } else {
        dim3 grid(OUT_F / 128, M / 128);
        band_gemm_f32<<<grid, 256, 0, stream>>>(x, wv, bias, out, M);
    }
}

// Round 5
// 140.725 us; speedup vs baseline: 1.2098x; 1.2098x over previous
//
#include <hip/hip_runtime.h>
#include <stdint.h>

#define IN_F  4096
#define OUT_F 4096
#define BW    512
#define WB2   1280   // padded k-window per 256-col tile: [bcol-512, bcol+768)
#define BM    256
#define BN    256

typedef __bf16 bf16x8 __attribute__((ext_vector_type(8)));
typedef float  f32x4  __attribute__((ext_vector_type(4)));

__device__ __forceinline__ int band_start(int o) {
    if (o <= 512)  return o * 513 + ((o * (o - 1)) >> 1);
    if (o <= 3584) return 393472 + (o - 512) * 1025;
    const int d = o - 3584;
    return 3542272 + (((1024 + 4609 - o) * d) >> 1);
}

__device__ __forceinline__ uint16_t f32_to_bf16(float f) {
    uint32_t u = __builtin_bit_cast(uint32_t, f);
    u += 0x7FFFu + ((u >> 16) & 1u);   // RNE
    return (uint16_t)(u >> 16);
}

// ---- pass 1: x fp32 -> bf16 dense [M][4096]
__global__ __launch_bounds__(256) void cvt_x(const float* __restrict__ x,
                                             uint16_t* __restrict__ xb, int n4) {
    const int stride = gridDim.x * 256;
    for (int i = blockIdx.x * 256 + threadIdx.x; i < n4; i += stride) {
        const float4 v = reinterpret_cast<const float4*>(x)[i];
        const uint32_t lo = (uint32_t)f32_to_bf16(v.x) | ((uint32_t)f32_to_bf16(v.y) << 16);
        const uint32_t hi = (uint32_t)f32_to_bf16(v.z) | ((uint32_t)f32_to_bf16(v.w) << 16);
        reinterpret_cast<uint2*>(xb)[i] = make_uint2(lo, hi);
    }
}

// ---- pass 2: densify band -> wd[o][j], j indexes k = (o&~255)-512+j, zero outside band
__global__ __launch_bounds__(256) void cvt_w(const float* __restrict__ wv,
                                             uint16_t* __restrict__ wd) {
    const int o = blockIdx.y;
    const int j = blockIdx.x * 256 + threadIdx.x;     // 0..1279
    const int i = (o & ~(BM - 1)) - BW + j;
    uint16_t v = 0;
    if (i >= o - BW && i <= o + BW && i >= 0 && i < IN_F) {
        const int lo = (o > BW) ? (o - BW) : 0;
        v = f32_to_bf16(wv[band_start(o) + (i - lo)]);
    }
    wd[o * WB2 + j] = v;
}

// ---- pass 3: 256x256, BK=64, ring-2, one barrier + one vmcnt(0)/tile, stages at top
__global__ __launch_bounds__(512, 1) void band_gemm_v5(
    const uint16_t* __restrict__ xb,
    const uint16_t* __restrict__ wd,
    const float* __restrict__ bias,
    float* __restrict__ out)
{
    __shared__ __align__(128) uint8_t lds[131072];   // 2 bufs x {A 32K, B 32K}

    // bx-grouped XCD mapping: XCD x owns column panels {2x, 2x+1}; B stays L2-hot
    const int id  = blockIdx.x;
    const int xcd = id & 7;
    const int r   = id >> 3;            // 0..63
    const int bx  = 2 * xcd + (r & 1);  // 0..15
    const int by  = r >> 1;             // 0..31
    const int brow = by * BM;
    const int bcol = bx * BN;

    const int wlo    = bcol - BW;
    const int kstart = wlo > 0 ? wlo : 0;                       // multiple of 256
    const int kend   = (bcol + BN + BW) < IN_F ? (bcol + BN + BW) : IN_F;
    const int nt     = (kend - kstart) >> 6;                    // 12..20 K64 tiles
    const int j0     = kstart - wlo;                            // 0/256/512

    const int tid  = threadIdx.x;
    const int w    = tid >> 6;
    const int lane = tid & 63;
    const int ln   = lane & 15;
    const int kc   = lane >> 4;
    const int wm   = w >> 2;            // 0..1  (M half, 128 rows)
    const int wn   = w & 3;             // 0..3  (N quarter, 64 cols)

    // staging: unit = 64 rows x 128 B (8 KB, one gload across 512 threads)
    // LDS(row, chunk c) holds global chunk c ^ (row & 7)   [chunk = 16 B]
    const int srow = tid >> 3;          // 0..63
    const int csrc = (tid & 7) ^ (srow & 7);
    const uint16_t* aSrc = xb + (size_t)(brow + srow) * IN_F + kstart + csrc * 8;
    const uint16_t* bSrc = wd + (size_t)(bcol + srow) * WB2 + j0 + csrc * 8;

#define GLOAD(srcp, dst_off)                                                             \
    __builtin_amdgcn_global_load_lds(                                                    \
        (const __attribute__((address_space(1))) uint32_t*)(srcp),                       \
        (__attribute__((address_space(3))) uint32_t*)(lds + (dst_off) + (w << 10)),      \
        16, 0, 0)

    // stage K64 tile ts into buffer base sb: A units rows 0-63,64-127,128-191,192-255; B same
#define STAGE(ts_, sb_) {                                                                \
        const uint16_t* as_ = aSrc + (ts_) * 64;                                         \
        const uint16_t* bs_ = bSrc + (ts_) * 64;                                         \
        GLOAD(as_,                        (sb_) + 0);                                    \
        GLOAD(as_ + (size_t)64  * IN_F,   (sb_) + 8192);                                 \
        GLOAD(as_ + (size_t)128 * IN_F,   (sb_) + 16384);                                \
        GLOAD(as_ + (size_t)192 * IN_F,   (sb_) + 24576);                                \
        GLOAD(bs_,                        (sb_) + 32768);                                 \
        GLOAD(bs_ + (size_t)64  * WB2,    (sb_) + 40960);                                \
        GLOAD(bs_ + (size_t)128 * WB2,    (sb_) + 49152);                                \
        GLOAD(bs_ + (size_t)192 * WB2,    (sb_) + 57344); }

    // fragment offsets: row stride 128 B; stored chunk = logical ^ (row&7), row&7 == ln&7
    // k-step 1 = byte offset ^ 64 (chunk ^ 4). Proven zero-conflict geometry.
    const int cswz = (kc ^ (ln & 7)) << 4;
    int aOff[8], bOff[4];
    #pragma unroll
    for (int a = 0; a < 8; ++a) aOff[a] = ((wm * 128 + a * 16 + ln) << 7) + cswz;
    #pragma unroll
    for (int n = 0; n < 4; ++n) bOff[n] = 32768 + ((wn * 64 + n * 16 + ln) << 7) + cswz;

    f32x4 acc[8][4] = {};

    // prologue: stage tile 0 -> buf 0
    STAGE(0, 0);
    asm volatile("s_waitcnt vmcnt(0)" ::: "memory");
    __builtin_amdgcn_s_barrier();

    for (int t = 0; t < nt; ++t) {
        const int cur = (t & 1) << 16;

        // issue next tile's 8 gloads FIRST (latency hidden under this tile's compute)
        if (t + 1 < nt) STAGE(t + 1, cur ^ 65536);

        // B frags: all 4 n x 2 k (32 VGPR), reused across both m-groups
        bf16x8 bfr[4][2];
        #pragma unroll
        for (int n = 0; n < 4; ++n) {
            bfr[n][0] = *(const bf16x8*)(lds + cur + bOff[n]);
            bfr[n][1] = *(const bf16x8*)(lds + cur + (bOff[n] ^ 64));
        }

        #pragma unroll
        for (int mq = 0; mq < 2; ++mq) {
            bf16x8 af[4][2];
            #pragma unroll
            for (int a = 0; a < 4; ++a) {
                af[a][0] = *(const bf16x8*)(lds + cur + aOff[mq * 4 + a]);
                af[a][1] = *(const bf16x8*)(lds + cur + (aOff[mq * 4 + a] ^ 64));
            }
            __builtin_amdgcn_s_setprio(1);
            #pragma unroll
            for (int a = 0; a < 4; ++a)
                #pragma unroll
                for (int n = 0; n < 4; ++n) {
                    acc[mq * 4 + a][n] = __builtin_amdgcn_mfma_f32_16x16x32_bf16(
                        af[a][0], bfr[n][0], acc[mq * 4 + a][n], 0, 0, 0);
                    acc[mq * 4 + a][n] = __builtin_amdgcn_mfma_f32_16x16x32_bf16(
                        af[a][1], bfr[n][1], acc[mq * 4 + a][n], 0, 0, 0);
                }
            __builtin_amdgcn_s_setprio(0);
        }

        // single drain + barrier per K64: stages were issued ~full-tile earlier
        asm volatile("s_waitcnt vmcnt(0)" ::: "memory");
        __builtin_amdgcn_s_barrier();
    }
#undef STAGE
#undef GLOAD

    // epilogue: C/D map col = lane&15, row = (lane>>4)*4 + q
    const int ocol = bcol + wn * 64 + ln;
    float bsv[4];
    #pragma unroll
    for (int n = 0; n < 4; ++n) bsv[n] = bias[ocol + n * 16];

    #pragma unroll
    for (int a = 0; a < 8; ++a) {
        #pragma unroll
        for (int q = 0; q < 4; ++q) {
            const int row = brow + wm * 128 + a * 16 + (kc << 2) + q;
            float* po = out + (size_t)row * OUT_F + ocol;
            #pragma unroll
            for (int n = 0; n < 4; ++n)
                po[n * 16] = acc[a][n][q] + bsv[n];
        }
    }
}

// ---- fallback (ws too small / odd M): fp32 tiled kernel, known correct
__global__ __launch_bounds__(256) void band_gemm_f32(
    const float* __restrict__ x, const float* __restrict__ wv,
    const float* __restrict__ bias, float* __restrict__ out, int M)
{
    __shared__ float Xs[128][33];
    __shared__ float Ws[32][130];
    const int tid = threadIdx.x;
    const int tx = tid & 15, ty = tid >> 4;
    const int bcol = blockIdx.x * 128, brow = blockIdx.y * 128;
    const int klo = (bcol >= BW) ? (bcol - BW) : 0;
    const int khi = min(IN_F, bcol + 128 + BW);
    float acc[8][8];
    #pragma unroll
    for (int a = 0; a < 8; ++a)
        #pragma unroll
        for (int b = 0; b < 8; ++b) acc[a][b] = 0.f;
    const int xc4 = (tid & 7) * 4, xr0 = tid >> 3;
    const int wc = tid & 31, wr0 = tid >> 5;
    for (int k0 = klo; k0 < khi; k0 += 32) {
        #pragma unroll
        for (int p = 0; p < 4; ++p) {
            const int r = xr0 + 32 * p;
            const float4 v = *reinterpret_cast<const float4*>(&x[(size_t)(brow + r) * IN_F + (k0 + xc4)]);
            Xs[r][xc4 + 0] = v.x; Xs[r][xc4 + 1] = v.y; Xs[r][xc4 + 2] = v.z; Xs[r][xc4 + 3] = v.w;
        }
        const int i = k0 + wc;
        #pragma unroll
        for (int p = 0; p < 16; ++p) {
            const int rr = wr0 + 8 * p;
            const int o = bcol + rr;
            const int lo = (o >= BW) ? (o - BW) : 0;
            float v = 0.f;
            if (i >= o - BW && i <= o + BW) v = wv[band_start(o) + (i - lo)];
            Ws[wc][rr] = v;
        }
        __syncthreads();
        #pragma unroll
        for (int k = 0; k < 32; ++k) {
            float am[8];
            #pragma unroll
            for (int a = 0; a < 8; ++a) am[a] = Xs[ty * 8 + a][k];
            float bo[8];
            #pragma unroll
            for (int b = 0; b < 4; ++b) { bo[b] = Ws[k][tx * 4 + b]; bo[4 + b] = Ws[k][tx * 4 + 64 + b]; }
            #pragma unroll
            for (int a = 0; a < 8; ++a)
                #pragma unroll
                for (int b = 0; b < 8; ++b) acc[a][b] = fmaf(am[a], bo[b], acc[a][b]);
        }
        __syncthreads();
    }
    #pragma unroll
    for (int a = 0; a < 8; ++a) {
        const size_t row = (size_t)(brow + ty * 8 + a);
        #pragma unroll
        for (int b = 0; b < 4; ++b) {
            out[row * OUT_F + bcol + tx * 4 + b]      = acc[a][b]     + bias[bcol + tx * 4 + b];
            out[row * OUT_F + bcol + tx * 4 + 64 + b] = acc[a][4 + b] + bias[bcol + tx * 4 + 64 + b];
        }
    }
}

extern "C" void kernel_launch(void* const* d_in, const int* in_sizes, int n_in,
                              void* d_out, int out_size, void* d_ws, size_t ws_size,
                              hipStream_t stream) {
    const float* x    = (const float*)d_in[0];
    const float* wv   = (const float*)d_in[1];
    const float* bias = (const float*)d_in[2];
    float* out        = (float*)d_out;

    const int M = in_sizes[0] / IN_F;                         // 8192
    const size_t xb_bytes = (size_t)M * IN_F * 2;             // 64 MB
    const size_t wd_bytes = (size_t)OUT_F * WB2 * 2;          // 10.5 MB

    if (ws_size >= xb_bytes + wd_bytes && (M % BM) == 0) {
        uint16_t* xb  = (uint16_t*)d_ws;
        uint16_t* wdp = (uint16_t*)((uint8_t*)d_ws + xb_bytes);
        cvt_x<<<2048, 256, 0, stream>>>(x, xb, M * IN_F / 4);
        cvt_w<<<dim3(WB2 / 256, OUT_F), 256, 0, stream>>>(wv, wdp);
        band_gemm_v5<<<(M / BM) * (OUT_F / BN), 512, 0, stream>>>(xb, wdp, bias, out);
    } else {
        dim3 grid(OUT_F / 128, M / 128);
        band_gemm_f32<<<grid, 256, 0, stream>>>(x, wv, bias, out, M);
    }
}